// Round 10
// baseline (2422.204 us; speedup 1.0000x reference)
//
#include <hip/hip_runtime.h>
#include <cstdint>

#define B_ 4
#define H_ 16
#define S_ 2048
#define D_ 64

// fold temperature (1/8) and log2(e) into q so exp(x) == exp2(scaled dot)
#define QSCALE (0.125f * 1.44269504088896f)

typedef _Float16 half8 __attribute__((ext_vector_type(8)));
typedef float f32x4 __attribute__((ext_vector_type(4)));
typedef float f32x16 __attribute__((ext_vector_type(16)));
typedef uint32_t u32x2 __attribute__((ext_vector_type(2)));
typedef uint32_t u32x4 __attribute__((ext_vector_type(4)));

// ---------- pre-kernels (FAST path) ----------

__global__ void cvt_qk_kernel(const float* __restrict__ q, const float* __restrict__ k,
                              _Float16* __restrict__ qh, _Float16* __restrict__ kh) {
    const int64_t N = (int64_t)B_ * H_ * S_ * D_;
    const int64_t step = (int64_t)gridDim.x * blockDim.x * 4;
    for (int64_t i = ((int64_t)blockIdx.x * blockDim.x + threadIdx.x) * 4; i < N; i += step) {
        float4 a = *reinterpret_cast<const float4*>(q + i);
        float4 b = *reinterpret_cast<const float4*>(k + i);
        _Float16 ah[4] = { (_Float16)(a.x * QSCALE), (_Float16)(a.y * QSCALE),
                           (_Float16)(a.z * QSCALE), (_Float16)(a.w * QSCALE) };
        _Float16 bh[4] = { (_Float16)b.x, (_Float16)b.y, (_Float16)b.z, (_Float16)b.w };
        *reinterpret_cast<u32x2*>(qh + i) = *reinterpret_cast<u32x2*>(ah);
        *reinterpret_cast<u32x2*>(kh + i) = *reinterpret_cast<u32x2*>(bh);
    }
}

// V [b,h,s,d] fp32 -> Vt [b,h,d,s] fp16
__global__ void transpose_v_kernel(const float* __restrict__ v, _Float16* __restrict__ vt) {
    const int bh = blockIdx.y;
    const int k0 = blockIdx.x * 64;
    const float* vp = v + (int64_t)bh * S_ * D_;
    _Float16* vtp = vt + (int64_t)bh * D_ * S_;
    const int t = threadIdx.x;
    const int d = t & 63;
    const int kc = t >> 6;
    _Float16 tmp[16];
#pragma unroll
    for (int j = 0; j < 16; ++j)
        tmp[j] = (_Float16)vp[(int64_t)(k0 + kc * 16 + j) * D_ + d];
    half8 a, b;
#pragma unroll
    for (int j = 0; j < 8; ++j) { a[j] = tmp[j]; b[j] = tmp[8 + j]; }
    half8* dst = reinterpret_cast<half8*>(vtp + (int64_t)d * S_ + k0 + kc * 16);
    dst[0] = a; dst[1] = b;
}

// mask int32 [b,q,k] -> bitmask; bit (k%32) of word (b*S+q)*64 + k/32
__global__ void pack_mask_kernel(const int* __restrict__ mask, uint32_t* __restrict__ mbits) {
    const int64_t groups = (int64_t)B_ * S_ * S_ / 64;
    const int lane = threadIdx.x & 63;
    const int64_t wstep = ((int64_t)gridDim.x * blockDim.x) >> 6;
    for (int64_t g = ((int64_t)blockIdx.x * blockDim.x + threadIdx.x) >> 6; g < groups; g += wstep) {
        int mv = mask[g * 64 + lane];
        unsigned long long bits = __ballot(mv != 0);
        if (lane == 0)
            *reinterpret_cast<unsigned long long*>(mbits + g * 2) = bits;
    }
}

// ---------- producer: exact Round-8 structure (known 677us, correct) ----------

template<bool FAST>
__global__ __launch_bounds__(256, 2) void attn_main(
    const float* __restrict__ qf, const float* __restrict__ kf, const float* __restrict__ vf,
    const int* __restrict__ maskI,
    const _Float16* __restrict__ qh, const _Float16* __restrict__ kh, const _Float16* __restrict__ vt,
    const uint32_t* __restrict__ mbits,
    float* __restrict__ out, float* __restrict__ attn)
{
    const int tid = threadIdx.x;
    const int w = tid >> 6;
    const int lane = tid & 63;
    const int c = lane & 31;
    const int hi = lane >> 5;
    const int qw = blockIdx.x * 128 + w * 32;
    const int64_t bh = (int64_t)blockIdx.z * H_ + blockIdx.y;
    const int64_t qrow = (int64_t)blockIdx.z * S_ + qw + c;

    half8 aq[4];
    if (FAST) {
        const _Float16* qp = qh + (bh * S_ + qw + c) * D_ + hi * 8;
#pragma unroll
        for (int kk = 0; kk < 4; ++kk)
            aq[kk] = *reinterpret_cast<const half8*>(qp + kk * 16);
    } else {
        const float* qp = qf + (bh * S_ + qw + c) * D_ + hi * 8;
#pragma unroll
        for (int kk = 0; kk < 4; ++kk)
#pragma unroll
            for (int j = 0; j < 8; ++j)
                aq[kk][j] = (_Float16)(qp[kk * 16 + j] * QSCALE);
    }

    const uint32_t* mrow = FAST ? (mbits + qrow * (S_ / 32)) : nullptr;

    float l = 0.f;
    for (int g = 0; g < 16; ++g) {
        u32x4 mq;
        if (FAST) mq = *reinterpret_cast<const u32x4*>(mrow + g * 4);
#pragma unroll
        for (int u = 0; u < 4; ++u) {
            const int k0 = (g * 4 + u) * 32;
            f32x16 acc;
#pragma unroll
            for (int r = 0; r < 16; ++r) acc[r] = 0.f;
            if (FAST) {
                const _Float16* kp = kh + (bh * S_ + k0 + c) * D_ + hi * 8;
#pragma unroll
                for (int kk = 0; kk < 4; ++kk) {
                    half8 bk = *reinterpret_cast<const half8*>(kp + kk * 16);
                    acc = __builtin_amdgcn_mfma_f32_32x32x16_f16(bk, aq[kk], acc, 0, 0, 0);
                }
            } else {
                const float* kp = kf + (bh * S_ + k0 + c) * D_ + hi * 8;
#pragma unroll
                for (int kk = 0; kk < 4; ++kk) {
                    half8 bk;
#pragma unroll
                    for (int j = 0; j < 8; ++j) bk[j] = (_Float16)kp[kk * 16 + j];
                    acc = __builtin_amdgcn_mfma_f32_32x32x16_f16(bk, aq[kk], acc, 0, 0, 0);
                }
            }
            uint32_t mw = 0;
            if (FAST) mw = mq[u] >> (hi * 4);
            float e[16];
#pragma unroll
            for (int r = 0; r < 16; ++r) {
                bool dead;
                if (FAST) {
                    dead = ((mw >> ((r & 3) + 8 * (r >> 2))) & 1u) == 0u;
                } else {
                    const int key = k0 + (r & 3) + 8 * (r >> 2) + 4 * hi;
                    dead = maskI[qrow * S_ + key] == 0;
                }
                e[r] = __builtin_exp2f(dead ? -1e30f : acc[r]);
            }
#pragma unroll
            for (int st = 1; st < 16; st <<= 1)
#pragma unroll
                for (int i = 0; i < 16; i += 2 * st) e[i] += e[i + st];
            l += e[0];
        }
    }
    const float lt = l + __shfl_xor(l, 32);
    const float rinv = 1.0f / lt;

    f32x16 o0, o1;
#pragma unroll
    for (int r = 0; r < 16; ++r) { o0[r] = 0.f; o1[r] = 0.f; }

    for (int g = 0; g < 16; ++g) {
        u32x4 mq;
        if (FAST) mq = *reinterpret_cast<const u32x4*>(mrow + g * 4);
#pragma unroll
        for (int u = 0; u < 4; ++u) {
            const int k0 = (g * 4 + u) * 32;
            f32x16 acc;
#pragma unroll
            for (int r = 0; r < 16; ++r) acc[r] = 0.f;
            if (FAST) {
                const _Float16* kp = kh + (bh * S_ + k0 + c) * D_ + hi * 8;
#pragma unroll
                for (int kk = 0; kk < 4; ++kk) {
                    half8 bk = *reinterpret_cast<const half8*>(kp + kk * 16);
                    acc = __builtin_amdgcn_mfma_f32_32x32x16_f16(bk, aq[kk], acc, 0, 0, 0);
                }
            } else {
                const float* kp = kf + (bh * S_ + k0 + c) * D_ + hi * 8;
#pragma unroll
                for (int kk = 0; kk < 4; ++kk) {
                    half8 bk;
#pragma unroll
                    for (int j = 0; j < 8; ++j) bk[j] = (_Float16)kp[kk * 16 + j];
                    acc = __builtin_amdgcn_mfma_f32_32x32x16_f16(bk, aq[kk], acc, 0, 0, 0);
                }
            }
            uint32_t mw = 0;
            if (FAST) mw = mq[u] >> (hi * 4);

            float* arow = attn + (bh * S_ + qw + c) * (int64_t)S_ + k0 + 4 * hi;
            uint32_t pk[8];
#pragma unroll
            for (int g4 = 0; g4 < 4; ++g4) {
                f32x4 pq;
#pragma unroll
                for (int e2 = 0; e2 < 4; ++e2) {
                    const int r = g4 * 4 + e2;
                    bool dead;
                    if (FAST) {
                        dead = ((mw >> (8 * g4 + e2)) & 1u) == 0u;
                    } else {
                        const int key = k0 + e2 + 8 * g4 + 4 * hi;
                        dead = maskI[qrow * S_ + key] == 0;
                    }
                    pq[e2] = __builtin_exp2f(dead ? -1e30f : acc[r]) * rinv;
                }
                *reinterpret_cast<f32x4*>(arow + 8 * g4) = pq;
                pk[2 * g4]     = __builtin_bit_cast(uint32_t, __builtin_amdgcn_cvt_pkrtz(pq[0], pq[1]));
                pk[2 * g4 + 1] = __builtin_bit_cast(uint32_t, __builtin_amdgcn_cvt_pkrtz(pq[2], pq[3]));
            }

            u32x2 rA = __builtin_amdgcn_permlane32_swap(pk[0], pk[2], false, false);
            u32x2 rB = __builtin_amdgcn_permlane32_swap(pk[1], pk[3], false, false);
            u32x2 rC = __builtin_amdgcn_permlane32_swap(pk[4], pk[6], false, false);
            u32x2 rD = __builtin_amdgcn_permlane32_swap(pk[5], pk[7], false, false);
            u32x4 fa0 = { rA[0], rB[0], rA[1], rB[1] };
            u32x4 fa1 = { rC[0], rD[0], rC[1], rD[1] };
            half8 pa0 = __builtin_bit_cast(half8, fa0);
            half8 pa1 = __builtin_bit_cast(half8, fa1);

            half8 bv00, bv01, bv10, bv11;
            if (FAST) {
                const _Float16* vp = vt + (bh * D_ + c) * S_ + k0 + hi * 8;
                bv00 = *reinterpret_cast<const half8*>(vp);
                bv01 = *reinterpret_cast<const half8*>(vp + 32 * S_);
                bv10 = *reinterpret_cast<const half8*>(vp + 16);
                bv11 = *reinterpret_cast<const half8*>(vp + 16 + 32 * S_);
            } else {
                const float* vp0 = vf + (bh * S_ + k0 + hi * 8) * D_ + c;
                const float* vp1 = vp0 + 16 * D_;
#pragma unroll
                for (int j = 0; j < 8; ++j) {
                    bv00[j] = (_Float16)vp0[j * D_];
                    bv01[j] = (_Float16)vp0[j * D_ + 32];
                    bv10[j] = (_Float16)vp1[j * D_];
                    bv11[j] = (_Float16)vp1[j * D_ + 32];
                }
            }
            o0 = __builtin_amdgcn_mfma_f32_32x32x16_f16(pa0, bv00, o0, 0, 0, 0);
            o1 = __builtin_amdgcn_mfma_f32_32x32x16_f16(pa0, bv01, o1, 0, 0, 0);
            o0 = __builtin_amdgcn_mfma_f32_32x32x16_f16(pa1, bv10, o0, 0, 0, 0);
            o1 = __builtin_amdgcn_mfma_f32_32x32x16_f16(pa1, bv11, o1, 0, 0, 0);
        }
    }

#pragma unroll
    for (int r = 0; r < 16; ++r) {
        const int row = (r & 3) + 8 * (r >> 2) + 4 * hi;
        float* op = out + (bh * S_ + qw + row) * D_;
        op[c] = o0[r];
        op[c + 32] = o1[r];
    }
}

// ---------- diagnostic ablation kernels (outputs go to ws junk / overwritten attn) ----------
// MODE 1: full pipeline, NO attn stores (everything else identical; o-sum to ws sink)
// MODE 2: pass A only (K load -> QK MFMA -> exp/mask -> reduce); l to ws sink
// MODE 3: attn-store stream only, identical addressing, junk values (attn later
//         fully overwritten by attn_main, so final output stays correct)

template<int MODE>
__global__ __launch_bounds__(256, 2) void attn_diag(
    const _Float16* __restrict__ qh, const _Float16* __restrict__ kh, const _Float16* __restrict__ vt,
    const uint32_t* __restrict__ mbits,
    float* __restrict__ attn, float* __restrict__ sink, int reps)
{
    const int tid = threadIdx.x;
    const int w = tid >> 6;
    const int lane = tid & 63;
    const int c = lane & 31;
    const int hi = lane >> 5;
    const int qw = blockIdx.x * 128 + w * 32;
    const int64_t bh = (int64_t)blockIdx.z * H_ + blockIdx.y;
    const int64_t qrow = (int64_t)blockIdx.z * S_ + qw + c;
    const uint32_t* mrow = mbits + qrow * (S_ / 32);

    float acc_sink = 0.f;

    if (MODE == 3) {
        for (int rep = 0; rep < reps; ++rep) {
            float base = (float)(rep + 1) * 1e-5f;
            for (int t = 0; t < 64; ++t) {
                float* arow = attn + (bh * S_ + qw + c) * (int64_t)S_ + t * 32 + 4 * hi;
#pragma unroll
                for (int g4 = 0; g4 < 4; ++g4) {
                    f32x4 pq = { base, base * 2.f, base * 3.f, base * 4.f };
                    *reinterpret_cast<f32x4*>(arow + 8 * g4) = pq;
                }
            }
        }
        if (lane == 0) sink[((bh * (S_ / 128) + blockIdx.x) * 4 + w)] = 0.f;
        return;
    }

    half8 aq[4];
    {
        const _Float16* qp = qh + (bh * S_ + qw + c) * D_ + hi * 8;
#pragma unroll
        for (int kk = 0; kk < 4; ++kk)
            aq[kk] = *reinterpret_cast<const half8*>(qp + kk * 16);
    }

    for (int rep = 0; rep < reps; ++rep) {
        // ---- pass A ----
        float l = 0.f;
        for (int g = 0; g < 16; ++g) {
            u32x4 mq = *reinterpret_cast<const u32x4*>(mrow + g * 4);
#pragma unroll
            for (int u = 0; u < 4; ++u) {
                const int k0 = (g * 4 + u) * 32;
                f32x16 acc;
#pragma unroll
                for (int r = 0; r < 16; ++r) acc[r] = 0.f;
                const _Float16* kp = kh + (bh * S_ + k0 + c) * D_ + hi * 8;
#pragma unroll
                for (int kk = 0; kk < 4; ++kk) {
                    half8 bk = *reinterpret_cast<const half8*>(kp + kk * 16);
                    acc = __builtin_amdgcn_mfma_f32_32x32x16_f16(bk, aq[kk], acc, 0, 0, 0);
                }
                uint32_t mw = mq[u] >> (hi * 4);
                float e[16];
#pragma unroll
                for (int r = 0; r < 16; ++r) {
                    bool dead = ((mw >> ((r & 3) + 8 * (r >> 2))) & 1u) == 0u;
                    e[r] = __builtin_exp2f(dead ? -1e30f : acc[r]);
                }
#pragma unroll
                for (int st = 1; st < 16; st <<= 1)
#pragma unroll
                    for (int i = 0; i < 16; i += 2 * st) e[i] += e[i + st];
                l += e[0];
            }
        }
        const float lt = l + __shfl_xor(l, 32);
        const float rinv = 1.0f / lt;
        acc_sink += lt;

        if (MODE == 2) continue;   // pass A only

        // ---- pass B without attn stores ----
        f32x16 o0, o1;
#pragma unroll
        for (int r = 0; r < 16; ++r) { o0[r] = 0.f; o1[r] = 0.f; }
        for (int g = 0; g < 16; ++g) {
            u32x4 mq = *reinterpret_cast<const u32x4*>(mrow + g * 4);
#pragma unroll
            for (int u = 0; u < 4; ++u) {
                const int k0 = (g * 4 + u) * 32;
                f32x16 acc;
#pragma unroll
                for (int r = 0; r < 16; ++r) acc[r] = 0.f;
                const _Float16* kp = kh + (bh * S_ + k0 + c) * D_ + hi * 8;
#pragma unroll
                for (int kk = 0; kk < 4; ++kk) {
                    half8 bk = *reinterpret_cast<const half8*>(kp + kk * 16);
                    acc = __builtin_amdgcn_mfma_f32_32x32x16_f16(bk, aq[kk], acc, 0, 0, 0);
                }
                uint32_t mw = mq[u] >> (hi * 4);
                uint32_t pk[8];
#pragma unroll
                for (int g4 = 0; g4 < 4; ++g4) {
                    f32x4 pq;
#pragma unroll
                    for (int e2 = 0; e2 < 4; ++e2) {
                        const int r = g4 * 4 + e2;
                        bool dead = ((mw >> (8 * g4 + e2)) & 1u) == 0u;
                        pq[e2] = __builtin_exp2f(dead ? -1e30f : acc[r]) * rinv;
                    }
                    // NO store: values stay live through pk -> PV -> o -> sink
                    pk[2 * g4]     = __builtin_bit_cast(uint32_t, __builtin_amdgcn_cvt_pkrtz(pq[0], pq[1]));
                    pk[2 * g4 + 1] = __builtin_bit_cast(uint32_t, __builtin_amdgcn_cvt_pkrtz(pq[2], pq[3]));
                }
                u32x2 rA = __builtin_amdgcn_permlane32_swap(pk[0], pk[2], false, false);
                u32x2 rB = __builtin_amdgcn_permlane32_swap(pk[1], pk[3], false, false);
                u32x2 rC = __builtin_amdgcn_permlane32_swap(pk[4], pk[6], false, false);
                u32x2 rD = __builtin_amdgcn_permlane32_swap(pk[5], pk[7], false, false);
                u32x4 fa0 = { rA[0], rB[0], rA[1], rB[1] };
                u32x4 fa1 = { rC[0], rD[0], rC[1], rD[1] };
                half8 pa0 = __builtin_bit_cast(half8, fa0);
                half8 pa1 = __builtin_bit_cast(half8, fa1);

                const _Float16* vp = vt + (bh * D_ + c) * S_ + k0 + hi * 8;
                half8 bv00 = *reinterpret_cast<const half8*>(vp);
                half8 bv01 = *reinterpret_cast<const half8*>(vp + 32 * S_);
                half8 bv10 = *reinterpret_cast<const half8*>(vp + 16);
                half8 bv11 = *reinterpret_cast<const half8*>(vp + 16 + 32 * S_);
                o0 = __builtin_amdgcn_mfma_f32_32x32x16_f16(pa0, bv00, o0, 0, 0, 0);
                o1 = __builtin_amdgcn_mfma_f32_32x32x16_f16(pa0, bv01, o1, 0, 0, 0);
                o0 = __builtin_amdgcn_mfma_f32_32x32x16_f16(pa1, bv10, o0, 0, 0, 0);
                o1 = __builtin_amdgcn_mfma_f32_32x32x16_f16(pa1, bv11, o1, 0, 0, 0);
            }
        }
#pragma unroll
        for (int r = 0; r < 16; ++r) acc_sink += o0[r] + o1[r];
    }

    sink[(((bh * (S_ / 128) + blockIdx.x) * 4 + w) * 64 + lane)] = acc_sink;
}

// ---------- launch ----------
extern "C" void kernel_launch(void* const* d_in, const int* in_sizes, int n_in,
                              void* d_out, int out_size, void* d_ws, size_t ws_size,
                              hipStream_t stream) {
    const float* q = (const float*)d_in[0];
    const float* k = (const float*)d_in[1];
    const float* v = (const float*)d_in[2];
    const int* mask = (const int*)d_in[3];
    float* out = (float*)d_out;
    float* attn = out + (int64_t)B_ * H_ * S_ * D_;

    const size_t nElem = (size_t)B_ * H_ * S_ * D_;           // 8388608
    const size_t maskWords = (size_t)B_ * S_ * (S_ / 32);     // 524288
    const size_t need = nElem * 2 * 3 + maskWords * 4;        // 52,428,800 B
    const size_t sinkBytes = (size_t)4096 * 64 * 4;           // 1 MB per sink
    const size_t needDiag = need + 2 * sinkBytes;

    dim3 grid(S_ / 128, H_, B_);
    if (d_ws != nullptr && ws_size >= need) {
        _Float16* qh = (_Float16*)d_ws;
        _Float16* kh = qh + nElem;
        _Float16* vt = kh + nElem;
        uint32_t* mb = (uint32_t*)(vt + nElem);
        cvt_qk_kernel<<<2048, 256, 0, stream>>>(q, k, qh, kh);
        transpose_v_kernel<<<dim3(S_ / 64, B_ * H_), 256, 0, stream>>>(v, vt);
        pack_mask_kernel<<<2048, 256, 0, stream>>>(mask, mb);

        if (ws_size >= needDiag) {
            float* sink1 = (float*)((char*)d_ws + need);
            float* sink2 = (float*)((char*)d_ws + need + sinkBytes);
            // ablation dispatches (junk outputs; attn fully overwritten below)
            attn_diag<1><<<grid, 256, 0, stream>>>(qh, kh, vt, mb, attn, sink1, 2);
            attn_diag<2><<<grid, 256, 0, stream>>>(qh, kh, vt, mb, attn, sink2, 3);
            attn_diag<3><<<grid, 256, 0, stream>>>(qh, kh, vt, mb, attn, sink1, 4);
        }

        attn_main<true><<<grid, 256, 0, stream>>>(q, k, v, mask, qh, kh, vt, mb, out, attn);
    } else {
        attn_main<false><<<grid, 256, 0, stream>>>(q, k, v, mask,
                                                   nullptr, nullptr, nullptr, nullptr, out, attn);
    }
}

// Round 11
// 683.194 us; speedup vs baseline: 3.5454x; 3.5454x over previous
//
#include <hip/hip_runtime.h>
#include <cstdint>

#define B_ 4
#define H_ 16
#define S_ 2048
#define D_ 64

// fold temperature (1/8) and log2(e) into q so exp(x) == exp2(scaled dot)
#define QSCALE (0.125f * 1.44269504088896f)

typedef _Float16 half8 __attribute__((ext_vector_type(8)));
typedef float f32x4 __attribute__((ext_vector_type(4)));
typedef float f32x16 __attribute__((ext_vector_type(16)));
typedef uint32_t u32x2 __attribute__((ext_vector_type(2)));
typedef uint32_t u32x4 __attribute__((ext_vector_type(4)));

// ---------- pre-kernels (FAST path) ----------

__global__ void cvt_qk_kernel(const float* __restrict__ q, const float* __restrict__ k,
                              _Float16* __restrict__ qh, _Float16* __restrict__ kh) {
    const int64_t N = (int64_t)B_ * H_ * S_ * D_;
    const int64_t step = (int64_t)gridDim.x * blockDim.x * 4;
    for (int64_t i = ((int64_t)blockIdx.x * blockDim.x + threadIdx.x) * 4; i < N; i += step) {
        float4 a = *reinterpret_cast<const float4*>(q + i);
        float4 b = *reinterpret_cast<const float4*>(k + i);
        _Float16 ah[4] = { (_Float16)(a.x * QSCALE), (_Float16)(a.y * QSCALE),
                           (_Float16)(a.z * QSCALE), (_Float16)(a.w * QSCALE) };
        _Float16 bh[4] = { (_Float16)b.x, (_Float16)b.y, (_Float16)b.z, (_Float16)b.w };
        *reinterpret_cast<u32x2*>(qh + i) = *reinterpret_cast<u32x2*>(ah);
        *reinterpret_cast<u32x2*>(kh + i) = *reinterpret_cast<u32x2*>(bh);
    }
}

// V [b,h,s,d] fp32 -> Vt [b,h,d,s] fp16
__global__ void transpose_v_kernel(const float* __restrict__ v, _Float16* __restrict__ vt) {
    const int bh = blockIdx.y;
    const int k0 = blockIdx.x * 64;
    const float* vp = v + (int64_t)bh * S_ * D_;
    _Float16* vtp = vt + (int64_t)bh * D_ * S_;
    const int t = threadIdx.x;
    const int d = t & 63;
    const int kc = t >> 6;
    _Float16 tmp[16];
#pragma unroll
    for (int j = 0; j < 16; ++j)
        tmp[j] = (_Float16)vp[(int64_t)(k0 + kc * 16 + j) * D_ + d];
    half8 a, b;
#pragma unroll
    for (int j = 0; j < 8; ++j) { a[j] = tmp[j]; b[j] = tmp[8 + j]; }
    half8* dst = reinterpret_cast<half8*>(vtp + (int64_t)d * S_ + k0 + kc * 16);
    dst[0] = a; dst[1] = b;
}

// mask int32 [b,q,k] -> bitmask; bit (k%32) of word (b*S+q)*64 + k/32
__global__ void pack_mask_kernel(const int* __restrict__ mask, uint32_t* __restrict__ mbits) {
    const int64_t groups = (int64_t)B_ * S_ * S_ / 64;
    const int lane = threadIdx.x & 63;
    const int64_t wstep = ((int64_t)gridDim.x * blockDim.x) >> 6;
    for (int64_t g = ((int64_t)blockIdx.x * blockDim.x + threadIdx.x) >> 6; g < groups; g += wstep) {
        int mv = mask[g * 64 + lane];
        unsigned long long bits = __ballot(mv != 0);
        if (lane == 0)
            *reinterpret_cast<unsigned long long*>(mbits + g * 2) = bits;
    }
}

// ---------- main attention kernel ----------
// 1D grid of 1024 blocks with XCD-aware decode: dispatcher round-robins
// blockIdx % 8 across XCDs, so we map ALL 16 q-tile blocks of one (b,h) to
// the SAME xcd ( xcd = fid&7; pair p = xcd + 8*(slot>>4); x = slot&15 ).
// Per-XCD live K/V working set ~1MB << 4MB L2 -> K/V fetched from HBM once,
// tile loads become L2 hits. Body identical to the Round-8 structure:
// 4 independent waves, swapped MFMA, per-lane softmax (no max-shift),
// direct f32x4 attn stores, PV A-frag via permlane32_swap. No LDS/barriers.

template<bool FAST>
__global__ __launch_bounds__(256, 2) void attn_main(
    const float* __restrict__ qf, const float* __restrict__ kf, const float* __restrict__ vf,
    const int* __restrict__ maskI,
    const _Float16* __restrict__ qh, const _Float16* __restrict__ kh, const _Float16* __restrict__ vt,
    const uint32_t* __restrict__ mbits,
    float* __restrict__ out, float* __restrict__ attn)
{
    const int tid = threadIdx.x;
    const int w = tid >> 6;
    const int lane = tid & 63;
    const int c = lane & 31;
    const int hi = lane >> 5;

    // ---- XCD-aware decode (bijective on 1024 blocks) ----
    const int fid = blockIdx.x;
    const int xcd = fid & 7;
    const int slot = fid >> 3;              // 0..127
    const int p = xcd + 8 * (slot >> 4);    // 0..63  == b*H + h
    const int x = slot & 15;                // q-tile index
    const int b = p >> 4;

    const int qw = x * 128 + w * 32;
    const int64_t bh = p;
    const int64_t qrow = (int64_t)b * S_ + qw + c;   // mask row for this lane

    half8 aq[4];
    if (FAST) {
        const _Float16* qp = qh + (bh * S_ + qw + c) * D_ + hi * 8;
#pragma unroll
        for (int kk = 0; kk < 4; ++kk)
            aq[kk] = *reinterpret_cast<const half8*>(qp + kk * 16);
    } else {
        const float* qp = qf + (bh * S_ + qw + c) * D_ + hi * 8;
#pragma unroll
        for (int kk = 0; kk < 4; ++kk)
#pragma unroll
            for (int j = 0; j < 8; ++j)
                aq[kk][j] = (_Float16)(qp[kk * 16 + j] * QSCALE);
    }

    const uint32_t* mrow = FAST ? (mbits + qrow * (S_ / 32)) : nullptr;

    // ================= Pass A: per-lane denominator =================
    float l = 0.f;
    for (int g = 0; g < 16; ++g) {
        u32x4 mq;
        if (FAST) mq = *reinterpret_cast<const u32x4*>(mrow + g * 4);
#pragma unroll
        for (int u = 0; u < 4; ++u) {
            const int k0 = (g * 4 + u) * 32;
            f32x16 acc;
#pragma unroll
            for (int r = 0; r < 16; ++r) acc[r] = 0.f;
            if (FAST) {
                const _Float16* kp = kh + (bh * S_ + k0 + c) * D_ + hi * 8;
#pragma unroll
                for (int kk = 0; kk < 4; ++kk) {
                    half8 bk = *reinterpret_cast<const half8*>(kp + kk * 16);
                    acc = __builtin_amdgcn_mfma_f32_32x32x16_f16(bk, aq[kk], acc, 0, 0, 0);
                }
            } else {
                const float* kp = kf + (bh * S_ + k0 + c) * D_ + hi * 8;
#pragma unroll
                for (int kk = 0; kk < 4; ++kk) {
                    half8 bk;
#pragma unroll
                    for (int j = 0; j < 8; ++j) bk[j] = (_Float16)kp[kk * 16 + j];
                    acc = __builtin_amdgcn_mfma_f32_32x32x16_f16(bk, aq[kk], acc, 0, 0, 0);
                }
            }
            uint32_t mw = 0;
            if (FAST) mw = mq[u] >> (hi * 4);
            float e[16];
#pragma unroll
            for (int r = 0; r < 16; ++r) {
                bool dead;
                if (FAST) {
                    dead = ((mw >> ((r & 3) + 8 * (r >> 2))) & 1u) == 0u;
                } else {
                    const int key = k0 + (r & 3) + 8 * (r >> 2) + 4 * hi;
                    dead = maskI[qrow * S_ + key] == 0;
                }
                e[r] = __builtin_exp2f(dead ? -1e30f : acc[r]);
            }
#pragma unroll
            for (int st = 1; st < 16; st <<= 1)
#pragma unroll
                for (int i = 0; i < 16; i += 2 * st) e[i] += e[i + st];
            l += e[0];
        }
    }
    const float lt = l + __shfl_xor(l, 32);
    const float rinv = 1.0f / lt;

    // ================= Pass B: recompute, normalize, store attn, PV =================
    f32x16 o0, o1;
#pragma unroll
    for (int r = 0; r < 16; ++r) { o0[r] = 0.f; o1[r] = 0.f; }

    for (int g = 0; g < 16; ++g) {
        u32x4 mq;
        if (FAST) mq = *reinterpret_cast<const u32x4*>(mrow + g * 4);
#pragma unroll
        for (int u = 0; u < 4; ++u) {
            const int k0 = (g * 4 + u) * 32;
            f32x16 acc;
#pragma unroll
            for (int r = 0; r < 16; ++r) acc[r] = 0.f;
            if (FAST) {
                const _Float16* kp = kh + (bh * S_ + k0 + c) * D_ + hi * 8;
#pragma unroll
                for (int kk = 0; kk < 4; ++kk) {
                    half8 bk = *reinterpret_cast<const half8*>(kp + kk * 16);
                    acc = __builtin_amdgcn_mfma_f32_32x32x16_f16(bk, aq[kk], acc, 0, 0, 0);
                }
            } else {
                const float* kp = kf + (bh * S_ + k0 + c) * D_ + hi * 8;
#pragma unroll
                for (int kk = 0; kk < 4; ++kk) {
                    half8 bk;
#pragma unroll
                    for (int j = 0; j < 8; ++j) bk[j] = (_Float16)kp[kk * 16 + j];
                    acc = __builtin_amdgcn_mfma_f32_32x32x16_f16(bk, aq[kk], acc, 0, 0, 0);
                }
            }
            uint32_t mw = 0;
            if (FAST) mw = mq[u] >> (hi * 4);

            float* arow = attn + (bh * S_ + qw + c) * (int64_t)S_ + k0 + 4 * hi;
            uint32_t pk[8];
#pragma unroll
            for (int g4 = 0; g4 < 4; ++g4) {
                f32x4 pq;
#pragma unroll
                for (int e2 = 0; e2 < 4; ++e2) {
                    const int r = g4 * 4 + e2;
                    bool dead;
                    if (FAST) {
                        dead = ((mw >> (8 * g4 + e2)) & 1u) == 0u;
                    } else {
                        const int key = k0 + e2 + 8 * g4 + 4 * hi;
                        dead = maskI[qrow * S_ + key] == 0;
                    }
                    pq[e2] = __builtin_exp2f(dead ? -1e30f : acc[r]) * rinv;
                }
                *reinterpret_cast<f32x4*>(arow + 8 * g4) = pq;
                pk[2 * g4]     = __builtin_bit_cast(uint32_t, __builtin_amdgcn_cvt_pkrtz(pq[0], pq[1]));
                pk[2 * g4 + 1] = __builtin_bit_cast(uint32_t, __builtin_amdgcn_cvt_pkrtz(pq[2], pq[3]));
            }

            u32x2 rA = __builtin_amdgcn_permlane32_swap(pk[0], pk[2], false, false);
            u32x2 rB = __builtin_amdgcn_permlane32_swap(pk[1], pk[3], false, false);
            u32x2 rC = __builtin_amdgcn_permlane32_swap(pk[4], pk[6], false, false);
            u32x2 rD = __builtin_amdgcn_permlane32_swap(pk[5], pk[7], false, false);
            u32x4 fa0 = { rA[0], rB[0], rA[1], rB[1] };
            u32x4 fa1 = { rC[0], rD[0], rC[1], rD[1] };
            half8 pa0 = __builtin_bit_cast(half8, fa0);
            half8 pa1 = __builtin_bit_cast(half8, fa1);

            half8 bv00, bv01, bv10, bv11;
            if (FAST) {
                const _Float16* vp = vt + (bh * D_ + c) * S_ + k0 + hi * 8;
                bv00 = *reinterpret_cast<const half8*>(vp);
                bv01 = *reinterpret_cast<const half8*>(vp + 32 * S_);
                bv10 = *reinterpret_cast<const half8*>(vp + 16);
                bv11 = *reinterpret_cast<const half8*>(vp + 16 + 32 * S_);
            } else {
                const float* vp0 = vf + (bh * S_ + k0 + hi * 8) * D_ + c;
                const float* vp1 = vp0 + 16 * D_;
#pragma unroll
                for (int j = 0; j < 8; ++j) {
                    bv00[j] = (_Float16)vp0[j * D_];
                    bv01[j] = (_Float16)vp0[j * D_ + 32];
                    bv10[j] = (_Float16)vp1[j * D_];
                    bv11[j] = (_Float16)vp1[j * D_ + 32];
                }
            }
            o0 = __builtin_amdgcn_mfma_f32_32x32x16_f16(pa0, bv00, o0, 0, 0, 0);
            o1 = __builtin_amdgcn_mfma_f32_32x32x16_f16(pa0, bv01, o1, 0, 0, 0);
            o0 = __builtin_amdgcn_mfma_f32_32x32x16_f16(pa1, bv10, o0, 0, 0, 0);
            o1 = __builtin_amdgcn_mfma_f32_32x32x16_f16(pa1, bv11, o1, 0, 0, 0);
        }
    }

#pragma unroll
    for (int r = 0; r < 16; ++r) {
        const int row = (r & 3) + 8 * (r >> 2) + 4 * hi;
        float* op = out + (bh * S_ + qw + row) * D_;
        op[c] = o0[r];
        op[c + 32] = o1[r];
    }
}

// ---------- launch ----------
extern "C" void kernel_launch(void* const* d_in, const int* in_sizes, int n_in,
                              void* d_out, int out_size, void* d_ws, size_t ws_size,
                              hipStream_t stream) {
    const float* q = (const float*)d_in[0];
    const float* k = (const float*)d_in[1];
    const float* v = (const float*)d_in[2];
    const int* mask = (const int*)d_in[3];
    float* out = (float*)d_out;
    float* attn = out + (int64_t)B_ * H_ * S_ * D_;

    const size_t nElem = (size_t)B_ * H_ * S_ * D_;           // 8388608
    const size_t maskWords = (size_t)B_ * S_ * (S_ / 32);     // 524288
    const size_t need = nElem * 2 * 3 + maskWords * 4;        // 52,428,800 B

    const int nblk = B_ * H_ * (S_ / 128);                    // 1024
    if (d_ws != nullptr && ws_size >= need) {
        _Float16* qh = (_Float16*)d_ws;
        _Float16* kh = qh + nElem;
        _Float16* vt = kh + nElem;
        uint32_t* mb = (uint32_t*)(vt + nElem);
        cvt_qk_kernel<<<2048, 256, 0, stream>>>(q, k, qh, kh);
        transpose_v_kernel<<<dim3(S_ / 64, B_ * H_), 256, 0, stream>>>(v, vt);
        pack_mask_kernel<<<2048, 256, 0, stream>>>(mask, mb);
        attn_main<true><<<nblk, 256, 0, stream>>>(q, k, v, mask, qh, kh, vt, mb, out, attn);
    } else {
        attn_main<false><<<nblk, 256, 0, stream>>>(q, k, v, mask,
                                                   nullptr, nullptr, nullptr, nullptr, out, attn);
    }
}